// Round 1
// baseline (289.496 us; speedup 1.0000x reference)
//
#include <hip/hip_runtime.h>
#include <math.h>

// NSVQ: N=131072 rows, D=64, K=1024 codes (fp32).
// out layout (flat f32): [0, N*D) quantized_input; [N*D] perplexity; [N*D+1, N*D+1+K) counts-as-float.
// ws layout: [0,4KB) cn (float[K]); [4KB,8KB) counts (int[K]); [8KB, ...) best (int[N]).

#define NSVQ_D 64
#define BN 128
#define BK 64
#define LDT 68   // padded LDS row stride (floats); keeps float4 alignment, <=2-way bank conflict

// ---------------- codebook norms ----------------
__global__ void nsvq_cnorm_kernel(const float* __restrict__ cb,
                                  float* __restrict__ cn, int K) {
  int k = blockIdx.x * blockDim.x + threadIdx.x;
  if (k >= K) return;
  const float4* p = (const float4*)(cb + (long)k * NSVQ_D);
  float s = 0.f;
#pragma unroll
  for (int i = 0; i < NSVQ_D / 4; ++i) {
    float4 v = p[i];
    s += v.x * v.x + v.y * v.y + v.z * v.z + v.w * v.w;
  }
  cn[k] = s;
}

// ---------------- argmin over codes (VALU GEMM-shaped) ----------------
__global__ __launch_bounds__(256, 3)
void nsvq_argmin_kernel(const float* __restrict__ x,
                        const float* __restrict__ cb,
                        const float* __restrict__ cn,
                        int* __restrict__ counts,
                        int* __restrict__ best,
                        int K) {
  __shared__ float xs[BN * LDT];
  __shared__ float cs[BK * LDT];
  const int tid = threadIdx.x;
  const int tr = tid >> 4;   // 0..15 (row group)
  const int tc = tid & 15;   // 0..15 (col group)
  const long brow = (long)blockIdx.x * BN;

  // stage x tile (128 x 64) -> LDS, coalesced float4
#pragma unroll
  for (int it = 0; it < 8; ++it) {
    int e4 = tid + it * 256;       // float4 index, 0..2047
    int row = e4 >> 4;             // 16 float4 per row
    int c4 = e4 & 15;
    float4 v = ((const float4*)(x + (brow + row) * NSVQ_D))[c4];
    *(float4*)&xs[row * LDT + c4 * 4] = v;
  }

  float bs[8];
  int bi[8];
#pragma unroll
  for (int i = 0; i < 8; ++i) { bs[i] = 3.4e38f; bi[i] = 0; }

  const int nchunk = K / BK;
  for (int chunk = 0; chunk < nchunk; ++chunk) {
    __syncthreads();  // protect cs (and xs on first iter)
#pragma unroll
    for (int it = 0; it < 4; ++it) {
      int e4 = tid + it * 256;     // 0..1023
      int row = e4 >> 4;
      int c4 = e4 & 15;
      float4 v = ((const float4*)(cb + ((long)chunk * BK + row) * NSVQ_D))[c4];
      *(float4*)&cs[row * LDT + c4 * 4] = v;
    }
    __syncthreads();

    float acc[8][4];
#pragma unroll
    for (int i = 0; i < 8; ++i)
#pragma unroll
      for (int j = 0; j < 4; ++j) acc[i][j] = 0.f;

#pragma unroll 4
    for (int d4 = 0; d4 < 16; ++d4) {
      float4 a[8], b[4];
#pragma unroll
      for (int i = 0; i < 8; ++i)
        a[i] = *(const float4*)&xs[(tr + 16 * i) * LDT + d4 * 4];
#pragma unroll
      for (int j = 0; j < 4; ++j)
        b[j] = *(const float4*)&cs[(tc + 16 * j) * LDT + d4 * 4];
#pragma unroll
      for (int i = 0; i < 8; ++i)
#pragma unroll
        for (int j = 0; j < 4; ++j) {
          acc[i][j] += a[i].x * b[j].x;
          acc[i][j] += a[i].y * b[j].y;
          acc[i][j] += a[i].z * b[j].z;
          acc[i][j] += a[i].w * b[j].w;
        }
    }

    // update per-row best with score = ||c||^2 - 2 x.c  (||x||^2 is row-constant)
#pragma unroll
    for (int j = 0; j < 4; ++j) {
      int k = chunk * BK + tc + 16 * j;
      float cnj = cn[k];
#pragma unroll
      for (int i = 0; i < 8; ++i) {
        float s = cnj - 2.0f * acc[i][j];
        if (s < bs[i] || (s == bs[i] && k < bi[i])) { bs[i] = s; bi[i] = k; }
      }
    }
  }

  // reduce best across the 16 col-threads (same 16-lane group within the wave)
#pragma unroll
  for (int i = 0; i < 8; ++i) {
    float s = bs[i];
    int k = bi[i];
#pragma unroll
    for (int off = 1; off < 16; off <<= 1) {
      float s2 = __shfl_xor(s, off, 64);
      int k2 = __shfl_xor(k, off, 64);
      if (s2 < s || (s2 == s && k2 < k)) { s = s2; k = k2; }
    }
    if (tc == 0) {
      long row = brow + tr + 16 * i;
      best[row] = k;
      atomicAdd(&counts[k], 1);
    }
  }
}

// ---------------- epilogue: noise-substitution quantization ----------------
__global__ __launch_bounds__(256)
void nsvq_epilogue_kernel(const float* __restrict__ x,
                          const float* __restrict__ cb,
                          const float* __restrict__ rv,
                          const int* __restrict__ best,
                          float* __restrict__ out) {
  const int tid = threadIdx.x;
  const long row = (long)blockIdx.x * 16 + (tid >> 4);  // 16 rows/block, 16 lanes/row
  const int l = tid & 15;
  const int k = best[row];

  float4 xv = ((const float4*)(x + row * NSVQ_D))[l];
  float4 cv = ((const float4*)(cb + (long)k * NSVQ_D))[l];
  float4 rr = ((const float4*)(rv + row * NSVQ_D))[l];

  float dx = xv.x - cv.x, dy = xv.y - cv.y, dz = xv.z - cv.z, dw = xv.w - cv.w;
  float dres = dx * dx + dy * dy + dz * dz + dw * dw;
  float drnd = rr.x * rr.x + rr.y * rr.y + rr.z * rr.z + rr.w * rr.w;
#pragma unroll
  for (int off = 1; off < 16; off <<= 1) {
    dres += __shfl_xor(dres, off, 64);
    drnd += __shfl_xor(drnd, off, 64);
  }
  float scale = sqrtf(dres) / (sqrtf(drnd) + 1e-12f);

  float4 o;
  o.x = xv.x + scale * rr.x;
  o.y = xv.y + scale * rr.y;
  o.z = xv.z + scale * rr.z;
  o.w = xv.w + scale * rr.w;
  ((float4*)(out + row * NSVQ_D))[l] = o;
}

// ---------------- perplexity + counts output ----------------
__global__ void nsvq_perp_kernel(const int* __restrict__ counts,
                                 float* __restrict__ out_tail,  // [0]=perp, [1..K]=counts
                                 float invN, int K) {
  int t = threadIdx.x;
  float v = 0.f;
  if (t < K) {
    int c = counts[t];
    out_tail[1 + t] = (float)c;
    float p = (float)c * invN;
    v = p * logf(p + 1e-12f);
  }
#pragma unroll
  for (int off = 1; off < 64; off <<= 1) v += __shfl_xor(v, off, 64);
  __shared__ float red[16];
  int wid = t >> 6;
  if ((t & 63) == 0) red[wid] = v;
  __syncthreads();
  if (t == 0) {
    float s = 0.f;
    int nw = (blockDim.x + 63) / 64;
    for (int w = 0; w < nw; ++w) s += red[w];
    out_tail[0] = expf(-s);
  }
}

extern "C" void kernel_launch(void* const* d_in, const int* in_sizes, int n_in,
                              void* d_out, int out_size, void* d_ws, size_t ws_size,
                              hipStream_t stream) {
  const float* x  = (const float*)d_in[0];
  const float* cb = (const float*)d_in[1];
  const float* rv = (const float*)d_in[2];
  float* out = (float*)d_out;

  const int D = NSVQ_D;
  const int N = in_sizes[0] / D;   // 131072
  const int K = in_sizes[1] / D;   // 1024

  float* cn   = (float*)d_ws;
  int* counts = (int*)((char*)d_ws + 4096);
  int* best   = (int*)((char*)d_ws + 8192);

  hipMemsetAsync(counts, 0, (size_t)K * sizeof(int), stream);
  nsvq_cnorm_kernel<<<(K + 255) / 256, 256, 0, stream>>>(cb, cn, K);
  nsvq_argmin_kernel<<<N / BN, 256, 0, stream>>>(x, cb, cn, counts, best, K);
  nsvq_epilogue_kernel<<<N / 16, 256, 0, stream>>>(x, cb, rv, best, out);
  nsvq_perp_kernel<<<1, 1024, 0, stream>>>(counts, out + (size_t)N * D, 1.0f / (float)N, K);
}